// Round 8
// baseline (513.779 us; speedup 1.0000x reference)
//
#include <hip/hip_runtime.h>

typedef unsigned short u16;
typedef unsigned int   u32;
typedef short bf16x8 __attribute__((ext_vector_type(8)));   // 8 bf16 (4 VGPRs)
typedef unsigned short u16x8 __attribute__((ext_vector_type(8)));
typedef float f32x4 __attribute__((ext_vector_type(4)));

__device__ __forceinline__ float bf2f(u16 u) {
    u32 x = ((u32)u) << 16;
    return __builtin_bit_cast(float, x);
}
__device__ __forceinline__ u16 f2bf(float f) {
    u32 u = __builtin_bit_cast(u32, f);
    u += 0x7fffu + ((u >> 16) & 1u);   // RNE
    return (u16)(u >> 16);
}
// fast tanh-gelu via v_exp (no libm tanhf in the epilogue)
__device__ __forceinline__ float gelu_f(float x) {
    const float u = 0.7978845608028654f * (x + 0.044715f * x * x * x);
    const float e = __expf(-2.f * fabsf(u));
    const float t = __builtin_copysignf((1.f - e) / (1.f + e), u);
    return 0.5f * x * (1.f + t);
}
// async global->LDS DMA, 16 B per lane; LDS dest must be wave-uniform base (m97 path)
__device__ __forceinline__ void glds16(const u16* g, u16* l) {
    __builtin_amdgcn_global_load_lds((const __attribute__((address_space(1))) u32*)g,
                                     (__attribute__((address_space(3))) u32*)l, 16, 0, 0);
}

// ---------------------------------------------------------------- dtype sniff
__global__ void sniff_kernel(const u32* __restrict__ p, int* __restrict__ flag) {
    const int i = threadIdx.x;                    // 0..63
    const u32 w = p[i * 8191 + 5];
    const u32 e = (w >> 7) & 0xFF;
    const bool absurd = (e >= 1 && e <= 90) || (e >= 160 && e <= 254);
    const unsigned long long m = __ballot(absurd);
    if (i == 0) *flag = (__popcll(m) >= 8) ? 1 : 0;
}

// ---------------------------------------------------------------- batched convert
struct CvtPack {
    const void* src[15];
    u16*        dst[15];
    int         n[15];
};
__global__ __launch_bounds__(256) void cvt_many(CvtPack pp, const int* __restrict__ flag) {
    const int f = *flag;
    const int j = blockIdx.y;
    const void* src = pp.src[j];
    u16* dst = pp.dst[j];
    const int n = pp.n[j];
    const int idx = blockIdx.x * 256 + threadIdx.x;
    const int stride = gridDim.x * 256;
    if (f) {
        const float* s = (const float*)src;
        for (int i = idx; i < n; i += stride) dst[i] = f2bf(s[i]);
    } else {
        const u16* s = (const u16*)src;
        for (int i = idx; i < n; i += stride) dst[i] = s[i];
    }
}

// ---------------------------------------------------------------- transpose+convert
// src[Kd][Nd] (f32 or bf16 per flag) -> dst[Nd][Kd] bf16. grid (Nd/32, Kd/32).
__global__ __launch_bounds__(256) void transpose_cv(const void* __restrict__ src,
                                                    u16* __restrict__ dst,
                                                    int Kd, int Nd,
                                                    const int* __restrict__ flag) {
    const int f = *flag;
    __shared__ u16 t[32][33];
    const int tx = threadIdx.x & 31, ty = threadIdx.x >> 5;   // ty 0..7
    const int x  = blockIdx.x * 32 + tx;
    const int y0 = blockIdx.y * 32;
#pragma unroll
    for (int j = 0; j < 4; ++j) {
        const long idx = (long)(y0 + ty + j * 8) * Nd + x;
        t[ty + j * 8][tx] = f ? f2bf(((const float*)src)[idx]) : ((const u16*)src)[idx];
    }
    __syncthreads();
    const int xo = blockIdx.y * 32 + tx;
#pragma unroll
    for (int j = 0; j < 4; ++j)
        dst[(long)(blockIdx.x * 32 + ty + j * 8) * Kd + xo] = t[tx][ty + j * 8];
}

// ---------------------------------------------------------------- layernorm (in-place, bf16)
__global__ __launch_bounds__(256) void ln_kernel(u16* __restrict__ x,
                                                 const u16* __restrict__ g,
                                                 const u16* __restrict__ bta) {
    const int tid = threadIdx.x;
    u16* p = x + (long)blockIdx.x * 1024;
    float v[4];
    float s = 0.f, s2 = 0.f;
#pragma unroll
    for (int i = 0; i < 4; ++i) {
        v[i] = bf2f(p[tid + i * 256]);
        s += v[i]; s2 += v[i] * v[i];
    }
#pragma unroll
    for (int off = 32; off; off >>= 1) {
        s  += __shfl_xor(s, off, 64);
        s2 += __shfl_xor(s2, off, 64);
    }
    __shared__ float ps[8];
    if ((tid & 63) == 0) { ps[(tid >> 6) * 2] = s; ps[(tid >> 6) * 2 + 1] = s2; }
    __syncthreads();
    s  = ps[0] + ps[2] + ps[4] + ps[6];
    s2 = ps[1] + ps[3] + ps[5] + ps[7];
    const float mu  = s * (1.f / 1024.f);
    const float var = s2 * (1.f / 1024.f) - mu * mu;
    const float rs  = rsqrtf(var + 1e-5f);
#pragma unroll
    for (int i = 0; i < 4; ++i) {
        const int c = tid + i * 256;
        p[c] = f2bf((v[i] - mu) * rs * bf2f(g[c]) + bf2f(bta[c]));
    }
}

// ---------------------------------------------------------------- final layernorm
__global__ __launch_bounds__(256) void ln_out_kernel(const u16* __restrict__ xin,
                                                     const u16* __restrict__ g,
                                                     const u16* __restrict__ bta,
                                                     void* __restrict__ out,
                                                     const int* __restrict__ flag) {
    const int tid = threadIdx.x;
    const u16* p = xin + (long)blockIdx.x * 1024;
    float v[4];
    float s = 0.f, s2 = 0.f;
#pragma unroll
    for (int i = 0; i < 4; ++i) {
        v[i] = bf2f(p[tid + i * 256]);
        s += v[i]; s2 += v[i] * v[i];
    }
#pragma unroll
    for (int off = 32; off; off >>= 1) {
        s  += __shfl_xor(s, off, 64);
        s2 += __shfl_xor(s2, off, 64);
    }
    __shared__ float ps[8];
    if ((tid & 63) == 0) { ps[(tid >> 6) * 2] = s; ps[(tid >> 6) * 2 + 1] = s2; }
    __syncthreads();
    s  = ps[0] + ps[2] + ps[4] + ps[6];
    s2 = ps[1] + ps[3] + ps[5] + ps[7];
    const float mu  = s * (1.f / 1024.f);
    const float var = s2 * (1.f / 1024.f) - mu * mu;
    const float rs  = rsqrtf(var + 1e-5f);
    const int f = *flag;
    if (f) {
        float* o = (float*)out + (long)blockIdx.x * 1024;
#pragma unroll
        for (int i = 0; i < 4; ++i) {
            const int c = tid + i * 256;
            o[c] = (v[i] - mu) * rs * bf2f(g[c]) + bf2f(bta[c]);
        }
    } else {
        u16* o = (u16*)out + (long)blockIdx.x * 1024;
#pragma unroll
        for (int i = 0; i < 4; ++i) {
            const int c = tid + i * 256;
            o[c] = f2bf((v[i] - mu) * rs * bf2f(g[c]) + bf2f(bta[c]));
        }
    }
}

// ---------------------------------------------------------------- GEMM v2 (r4-exact)
// C[M,N] = A[M,K] @ W[K,N] (+bias, +res / gelu), W pre-transposed Bt[N,K].
// BM x BN tile, BK=64, 8 waves (512 thr), wave grid 2(M) x 4(N).
// Double-buffered global_load_lds with XOR-swizzled layout (pre-swizzled global
// source, swizzled ds_read) -> conflict-free at 128 B rows. One barrier/K-step.
// rule #19 (confirmed r5-r7): the instantiation SET perturbs codegen; the
// <128,64> siblings doubled the fc dispatch. Instantiation set is pinned to
// {256x256, 128x128, 128x256} - do not add variants without re-benching fc.
template <int BM, int BN, int EPI>    // EPI: 0 = bias, 1 = bias+residual, 2 = bias+gelu
__global__ __launch_bounds__(512, (BM + BN) <= 256 ? 4 : 2)
void gemm2(const u16* __restrict__ A, const u16* __restrict__ Bt,
           const u16* __restrict__ bias, const u16* __restrict__ res,
           u16* __restrict__ C, int N, int K) {
    constexpr int WM  = BM / 2, WN = BN / 4;       // per-wave output tile
    constexpr int MT  = WM / 16, NT = WN / 16;     // 16x16 fragments per wave
    constexpr int ACH = BM / 8;                    // 8-row DMA chunks in A
    constexpr int NCH = (BM + BN) / 8;             // total chunks per K-step
    constexpr int CPW = NCH / 8;                   // chunks per wave
    constexpr int BUF = (BM + BN) * 64;            // u16 elems per LDS buffer

    const int tid  = threadIdx.x;
    const int wave = tid >> 6, lane = tid & 63;
    const int quad = lane >> 4, l16 = lane & 15;
    const int wm = wave >> 2, wn = wave & 3;

    // bijective XCD-aware block swizzle (all grids are %8==0)
    const int gx  = gridDim.x;
    const int nwg = gx * gridDim.y;
    int lin = blockIdx.y * gx + blockIdx.x;
    lin = (lin & 7) * (nwg >> 3) + (lin >> 3);
    const int bx = lin % gx, by = lin / gx;
    const long m0 = (long)by * BM;
    const int  n0 = bx * BN;

    __shared__ u16 L[2][BUF];   // [A rows BM x 64 | B rows BN x 64], swizzled

    f32x4 acc[MT][NT];
#pragma unroll
    for (int i = 0; i < MT; ++i)
#pragma unroll
        for (int j = 0; j < NT; ++j) acc[i][j] = (f32x4){0.f, 0.f, 0.f, 0.f};

    // DMA chunk = 8 rows x 64 k = 1024 B. lane l -> row (l>>3), k-unit (l&7)^((l>>3)&7)
    const int ro   = lane >> 3;
    const int swzk = ((lane & 7) ^ (ro & 7)) << 3;   // pre-swizzled global k offset (elems)
    const u16* gsrc[CPW];
    u16*       ldst[CPW];
#pragma unroll
    for (int c = 0; c < CPW; ++c) {
        const int ch = wave + c * 8;
        const u16* base = (ch < ACH) ? A : Bt;
        const long grow = (ch < ACH) ? (m0 + ch * 8 + ro)
                                     : ((long)n0 + (ch - ACH) * 8 + ro);
        gsrc[c] = base + grow * K + swzk;
        ldst[c] = (u16*)&L[0][ch * 512];
    }

    auto stage = [&](int ib, int kt) {
#pragma unroll
        for (int c = 0; c < CPW; ++c)
            glds16(gsrc[c] + kt, ldst[c] + ib * BUF);
    };

    const int nk = K >> 6;
    stage(0, 0);
    for (int i = 0; i < nk; ++i) {
        const int ib = i & 1;
        __syncthreads();                 // drains vmcnt: buf[ib] staged; prev reads done
        if (i + 1 < nk) stage(ib ^ 1, (i + 1) << 6);
#pragma unroll
        for (int st = 0; st < 2; ++st) {
            bf16x8 af[MT], bfv[NT];
#pragma unroll
            for (int mt = 0; mt < MT; ++mt) {
                const int rr = wm * WM + mt * 16 + l16;
                af[mt] = *(const bf16x8*)&L[ib][rr * 64 + (((st * 4 + quad) ^ (rr & 7)) << 3)];
            }
#pragma unroll
            for (int nt = 0; nt < NT; ++nt) {
                const int rr = wn * WN + nt * 16 + l16;
                bfv[nt] = *(const bf16x8*)&L[ib][BM * 64 + rr * 64 +
                                                 (((st * 4 + quad) ^ (rr & 7)) << 3)];
            }
            __builtin_amdgcn_s_setprio(1);
#pragma unroll
            for (int mt = 0; mt < MT; ++mt)
#pragma unroll
                for (int nt = 0; nt < NT; ++nt)
                    acc[mt][nt] = __builtin_amdgcn_mfma_f32_16x16x32_bf16(af[mt], bfv[nt],
                                                                          acc[mt][nt], 0, 0, 0);
            __builtin_amdgcn_s_setprio(0);
        }
    }

    // D row = quad*4+r, col = l16 (m89/m91-verified)
#pragma unroll
    for (int mt = 0; mt < MT; ++mt)
#pragma unroll
        for (int r = 0; r < 4; ++r) {
            const long row = m0 + wm * WM + mt * 16 + quad * 4 + r;
#pragma unroll
            for (int nt = 0; nt < NT; ++nt) {
                const int col = n0 + wn * WN + nt * 16 + l16;
                float v = acc[mt][nt][r] + bf2f(bias[col]);
                if constexpr (EPI == 1) v += bf2f(res[row * N + col]);
                if constexpr (EPI == 2) v = gelu_f(v);
                C[row * N + col] = f2bf(v);
            }
        }
}

// ---------------------------------------------------------------- attention v4
// r4 structure + pairing (r7's adjacent pairing reverted: no measured gain).
// NEW: gated cross-lane max-reduce. The 16 shfl_xor max ops (4-deep serial
// chain x 4 rows) previously ran EVERY tile but their result is only consumed
// when a rescale fires. Lane-local max suffices for the trigger test:
// any(lane-local max > mrow+8) over the wave == cross-lane max > mrow+8.
// Skip-tiles (common case, defer-max) now skip the DS-pipe shuffles entirely.
#define KSTR 72   // 64 + 8 pad (rows stay 16B-aligned: 144 B)
#define MASKV -3.0e4f
template <bool CAUSAL>
__global__ __launch_bounds__(512) void attn3(const u16* __restrict__ Qb,
                                             const u16* __restrict__ Kb,
                                             const u16* __restrict__ Vb,
                                             u16* __restrict__ Ob,
                                             int qstride, int kvstride, int S) {
    const int tid  = threadIdx.x;
    const int wave = tid >> 6, lane = tid & 63;
    const int quad = lane >> 4, l16 = lane & 15;
    const int h = blockIdx.y, b = blockIdx.z;
    const long tokbase = (long)b * S;
    const int QT = S >> 6;

    int qtile;
    if (CAUSAL) qtile = (wave < 4) ? blockIdx.x : (QT - 1 - blockIdx.x);
    else        qtile = blockIdx.x * 2 + (wave >> 2);
    const int qbase = qtile * 64 + (wave & 3) * 16;       // wave's absolute q-row base
    const int nkt = CAUSAL ? (QT - blockIdx.x) : QT;      // tiles staged by block
    const int myn = CAUSAL ? (qtile + 1) : QT;            // tiles this wave computes

    __shared__ u16 K_lds[2][64 * 64];    // XOR-swizzled, 128 B rows
    __shared__ u16 Vt_lds[2][64 * KSTR]; // [d][key], padded rows
    __shared__ u16 P_lds[128 * KSTR];    // [qrow(128)][key], wave-private 16-row bands

    // Q fragments (A-operand: m=l16, k=quad*8+j), pre-scaled by 1/sqrt(64)
    const u16* qrow = Qb + (tokbase + qbase + l16) * qstride + h * 64;
    bf16x8 qf[2];
    qf[0] = *(const bf16x8*)(qrow + quad * 8);
    qf[1] = *(const bf16x8*)(qrow + 32 + quad * 8);
#pragma unroll
    for (int s8 = 0; s8 < 2; ++s8)
#pragma unroll
        for (int j = 0; j < 8; ++j)
            qf[s8][j] = (short)f2bf(bf2f((u16)qf[s8][j]) * 0.125f);   // exact (exp shift)

    f32x4 acc[4];
#pragma unroll
    for (int i = 0; i < 4; ++i) acc[i] = (f32x4){0.f, 0.f, 0.f, 0.f};
    float mrow[4], lsum[4];
#pragma unroll
    for (int r = 0; r < 4; ++r) { mrow[r] = MASKV; lsum[r] = 0.f; }

    // K staging: wave chunk = rows wave*8..wave*8+7 (1024 B linear in LDS).
    // Pre-swizzled global k-offset so linear DMA lands XOR-swizzled (rule #21).
    const int kro = lane >> 3;                       // row within chunk (0..7)
    const int ksw = ((lane & 7) ^ kro) << 3;         // swizzled k elem offset
    const u16* Kln = Kb + (tokbase + wave * 8 + kro) * kvstride + h * 64 + ksw;
    // V staging: thread t -> column d = t&63, keys vkg*8..vkg*8+7
    const int vd = tid & 63, vkg = tid >> 6;
    const u16* Vln = Vb + (tokbase + vkg * 8) * kvstride + h * 64 + vd;

    u16x8 vreg;
    auto loadV = [&](int kt) {
#pragma unroll
        for (int jj = 0; jj < 8; ++jj)
            vreg[jj] = Vln[((long)kt * 64 + jj) * kvstride];
    };

    // prologue: stage tile 0
    loadV(0);
    glds16(Kln, &K_lds[0][wave * 512]);
    *(u16x8*)(&Vt_lds[0][vd * KSTR + vkg * 8]) = vreg;
    __syncthreads();    // drains glds + V writes

    for (int kt = 0; kt < nkt; ++kt) {
        const int cur = kt & 1;
        const bool haveNext = (kt + 1 < nkt);
        if (haveNext) {   // issue next tile's loads early (hide under compute)
            glds16(Kln + (long)(kt + 1) * 64 * kvstride, &K_lds[cur ^ 1][wave * 512]);
            loadV(kt + 1);
        }
        if (kt < myn) {
            // QK^T (pre-scaled): D row(q) = quad*4+r, col(key) = l16
            float p[4][4];
#pragma unroll
            for (int nt = 0; nt < 4; ++nt) {
                f32x4 s = (f32x4){0.f, 0.f, 0.f, 0.f};
#pragma unroll
                for (int st = 0; st < 2; ++st) {
                    bf16x8 kf = *(const bf16x8*)(&K_lds[cur][(nt * 16 + l16) * 64 +
                                                  (((st * 4 + quad) ^ (l16 & 7)) << 3)]);
                    s = __builtin_amdgcn_mfma_f32_16x16x32_bf16(qf[st], kf, s, 0, 0, 0);
                }
#pragma unroll
                for (int r = 0; r < 4; ++r) p[nt][r] = s[r];
            }
            // causal mask: only the diagonal tile needs it (wave-uniform branch)
            if (CAUSAL && kt == qtile) {
#pragma unroll
                for (int nt = 0; nt < 4; ++nt)
#pragma unroll
                    for (int r = 0; r < 4; ++r) {
                        const int qg  = qbase + quad * 4 + r;
                        const int kgi = kt * 64 + nt * 16 + l16;
                        if (kgi > qg) p[nt][r] = MASKV;
                    }
            }
            // online softmax, defer-max (THR=8), GATED cross-lane reduce:
            // lane-local max decides; shuffles only on the (rare) firing tile.
            float lmax[4];
#pragma unroll
            for (int r = 0; r < 4; ++r)
                lmax[r] = fmaxf(fmaxf(p[0][r], p[1][r]), fmaxf(p[2][r], p[3][r]));
            bool need = false;
#pragma unroll
            for (int r = 0; r < 4; ++r) need |= (lmax[r] > mrow[r] + 8.f);
            if (__any(need)) {   // wave-uniform: full reduce + rescale
#pragma unroll
                for (int r = 0; r < 4; ++r) {
                    float m3 = lmax[r];
#pragma unroll
                    for (int off = 1; off <= 8; off <<= 1)
                        m3 = fmaxf(m3, __shfl_xor(m3, off, 64));
                    const float newm  = fmaxf(mrow[r], m3);
                    const float alpha = __expf(mrow[r] - newm);
                    mrow[r] = newm;
                    lsum[r] *= alpha;
#pragma unroll
                    for (int dt = 0; dt < 4; ++dt) acc[dt][r] *= alpha;
                }
            }
#pragma unroll
            for (int nt = 0; nt < 4; ++nt)
#pragma unroll
                for (int r = 0; r < 4; ++r) {
                    p[nt][r] = __expf(p[nt][r] - mrow[r]);   // bounded by e^8
                    lsum[r] += p[nt][r];                     // per-lane partial (deferred)
                }
            // P -> LDS (wave-private rows; PV below needs only lgkmcnt, no barrier)
#pragma unroll
            for (int nt = 0; nt < 4; ++nt)
#pragma unroll
                for (int r = 0; r < 4; ++r)
                    P_lds[(wave * 16 + quad * 4 + r) * KSTR + nt * 16 + l16] = f2bf(p[nt][r]);
            // PV: O[q][d] += P[q][key] * Vt[d][key]
#pragma unroll
            for (int st = 0; st < 2; ++st) {
                bf16x8 pf = *(const bf16x8*)(&P_lds[(wave * 16 + l16) * KSTR + st * 32 + quad * 8]);
#pragma unroll
                for (int dt = 0; dt < 4; ++dt) {
                    bf16x8 vf = *(const bf16x8*)(&Vt_lds[cur][(dt * 16 + l16) * KSTR +
                                                              st * 32 + quad * 8]);
                    acc[dt] = __builtin_amdgcn_mfma_f32_16x16x32_bf16(pf, vf, acc[dt], 0, 0, 0);
                }
            }
        }
        if (haveNext)   // write-late: V regs -> next buffer (vmcnt wait by compiler)
            *(u16x8*)(&Vt_lds[cur ^ 1][vd * KSTR + vkg * 8]) = vreg;
        __syncthreads();   // one barrier/tile: drains next-tile glds, publishes Vt
    }

#pragma unroll
    for (int r = 0; r < 4; ++r) {
        float rs = lsum[r];    // epilogue cross-lane sum reduce (deferred from loop)
#pragma unroll
        for (int off = 1; off <= 8; off <<= 1) rs += __shfl_xor(rs, off, 64);
        const float inv = 1.f / rs;
        const long row = tokbase + qbase + quad * 4 + r;
#pragma unroll
        for (int dt = 0; dt < 4; ++dt)
            Ob[row * 1024 + h * 64 + dt * 16 + l16] = f2bf(acc[dt][r] * inv);
    }
}

// ---------------------------------------------------------------- launch
extern "C" void kernel_launch(void* const* d_in, const int* in_sizes, int n_in,
                              void* d_out, int out_size, void* d_ws, size_t ws_size,
                              hipStream_t stream) {
    u16* ws = (u16*)d_ws;
    // ---- workspace layout (u16 elements) ----
    u16* Wt_attn  = ws + 0;          // 3072x1024
    u16* Wt_self  = ws + 3145728;    // 1024x1024
    u16* Wt_q     = ws + 4194304;    // 1024x1024
    u16* Wt_kv    = ws + 5242880;    // 2048x1024
    u16* Wt_cross = ws + 7340032;    // 1024x1024
    u16* Wt_fc    = ws + 8388608;    // 4096x1024
    u16* Wt_mlp   = ws + 12582912;   // 1024x4096 (ends 16777216)
    u16* qkv      = ws + 16777216;   // 4096x3072 (dead after self-attn)
    u16* q2       = ws + 16777216;   // 4096x1024 (reuse)
    u16* kv2      = ws + 20971520;   // 4096x2048 (reuse)
    u16* x2       = ws + 16777216;   // 4096x1024 (reuse; live into MLP)
    u16* hbuf     = ws + 20971520;   // 4096x4096 (reuse; ends 37748736)
    u16* abuf     = ws + 29360128;   // 4096x1024
    u16* x1       = ws + 33554432;   // 4096x1024 (ends 37748736)
    u16* xb       = ws + 37748736;   // 4096x1024 (converted x; dead after self-proj)
    u16* y3       = ws + 37748736;   // 4096x1024 (MLP out pre-LN; reuses xb slot)
    u16* ctxb     = ws + 41943040;   // 4096x1024 (converted ctx)
    u16* P        = ws + 46137344;   // param slots
    u16* cab = P;            u16* spb = P + 4096;  u16* qb  = P + 8192;
    u16* kvb = P + 12288;    u16* cpb = P + 16384; u16* fcb = P + 20480;
    u16* mpb = P + 24576;
    u16* l1g = P + 28672;  u16* l1b = P + 32768;
    u16* l2g = P + 36864;  u16* l2b = P + 40960;
    u16* l3g = P + 45056;  u16* l3b = P + 49152;
    int* flag = (int*)(ws + 46137344 + 53248);

    const dim3 tb(256);
    const dim3 tg(512);
    const int NTOK = 4096;

    // ---- dtype sniff on x ----
    sniff_kernel<<<1, 64, 0, stream>>>((const u32*)d_in[0], flag);

    // ---- convert activations + params to bf16 (single batched launch) ----
    CvtPack pp;
    pp.src[0] = d_in[0];  pp.dst[0] = xb;   pp.n[0] = NTOK * 1024;
    pp.src[1] = d_in[1];  pp.dst[1] = ctxb; pp.n[1] = NTOK * 1024;
    pp.src[2] = d_in[3];  pp.dst[2] = cab;  pp.n[2] = 3072;
    pp.src[3] = d_in[5];  pp.dst[3] = spb;  pp.n[3] = 1024;
    pp.src[4] = d_in[7];  pp.dst[4] = qb;   pp.n[4] = 1024;
    pp.src[5] = d_in[9];  pp.dst[5] = kvb;  pp.n[5] = 2048;
    pp.src[6] = d_in[11]; pp.dst[6] = cpb;  pp.n[6] = 1024;
    pp.src[7] = d_in[13]; pp.dst[7] = fcb;  pp.n[7] = 4096;
    pp.src[8] = d_in[15]; pp.dst[8] = mpb;  pp.n[8] = 1024;
    pp.src[9] = d_in[16]; pp.dst[9] = l1g;  pp.n[9] = 1024;
    pp.src[10] = d_in[17]; pp.dst[10] = l1b; pp.n[10] = 1024;
    pp.src[11] = d_in[18]; pp.dst[11] = l2g; pp.n[11] = 1024;
    pp.src[12] = d_in[19]; pp.dst[12] = l2b; pp.n[12] = 1024;
    pp.src[13] = d_in[20]; pp.dst[13] = l3g; pp.n[13] = 1024;
    pp.src[14] = d_in[21]; pp.dst[14] = l3b; pp.n[14] = 1024;
    cvt_many<<<dim3(256, 15), tb, 0, stream>>>(pp, flag);

    // ---- weight transposes (+convert): W[K,N] -> Wt[N,K] ----
    transpose_cv<<<dim3(96, 32),  tb, 0, stream>>>(d_in[2],  Wt_attn,  1024, 3072, flag);
    transpose_cv<<<dim3(32, 32),  tb, 0, stream>>>(d_in[4],  Wt_self,  1024, 1024, flag);
    transpose_cv<<<dim3(32, 32),  tb, 0, stream>>>(d_in[6],  Wt_q,     1024, 1024, flag);
    transpose_cv<<<dim3(64, 32),  tb, 0, stream>>>(d_in[8],  Wt_kv,    1024, 2048, flag);
    transpose_cv<<<dim3(32, 32),  tb, 0, stream>>>(d_in[10], Wt_cross, 1024, 1024, flag);
    transpose_cv<<<dim3(128, 32), tb, 0, stream>>>(d_in[12], Wt_fc,    1024, 4096, flag);
    transpose_cv<<<dim3(32, 128), tb, 0, stream>>>(d_in[14], Wt_mlp,   4096, 1024, flag);

    // --- causal self-attention ---
    gemm2<256, 256, 0><<<dim3(12, 16), tg, 0, stream>>>(xb, Wt_attn, cab, nullptr, qkv, 3072, 1024);
    attn3<true><<<dim3(16, 16, 4), tg, 0, stream>>>(qkv, qkv + 1024, qkv + 2048, abuf,
                                                    3072, 3072, 1024);
    gemm2<128, 128, 1><<<dim3(8, 32), tg, 0, stream>>>(abuf, Wt_self, spb, xb, x1, 1024, 1024);
    ln_kernel<<<NTOK, tb, 0, stream>>>(x1, l1g, l1b);

    // --- cross-attention ---
    gemm2<128, 128, 0><<<dim3(8, 32),  tg, 0, stream>>>(x1,   Wt_q,  qb,  nullptr, q2,  1024, 1024);
    gemm2<128, 256, 0><<<dim3(8, 32), tg, 0, stream>>>(ctxb, Wt_kv, kvb, nullptr, kv2, 2048, 1024);
    attn3<false><<<dim3(8, 16, 4), tg, 0, stream>>>(q2, kv2, kv2 + 1024, abuf,
                                                    1024, 2048, 1024);
    gemm2<128, 128, 1><<<dim3(8, 32), tg, 0, stream>>>(abuf, Wt_cross, cpb, x1, x2, 1024, 1024);
    ln_kernel<<<NTOK, tb, 0, stream>>>(x2, l2g, l2b);

    // --- MLP ---
    gemm2<256, 256, 2><<<dim3(16, 16), tg, 0, stream>>>(x2, Wt_fc, fcb, nullptr, hbuf, 4096, 1024);
    gemm2<128, 128, 1><<<dim3(8, 32), tg, 0, stream>>>(hbuf, Wt_mlp, mpb, x2, y3, 1024, 4096);
    ln_out_kernel<<<NTOK, tb, 0, stream>>>(y3, l3g, l3b, d_out, flag);
}

// Round 9
// 494.046 us; speedup vs baseline: 1.0399x; 1.0399x over previous
//
#include <hip/hip_runtime.h>

typedef unsigned short u16;
typedef unsigned int   u32;
typedef short bf16x8 __attribute__((ext_vector_type(8)));   // 8 bf16 (4 VGPRs)
typedef unsigned short u16x8 __attribute__((ext_vector_type(8)));
typedef float f32x4 __attribute__((ext_vector_type(4)));

__device__ __forceinline__ float bf2f(u16 u) {
    u32 x = ((u32)u) << 16;
    return __builtin_bit_cast(float, x);
}
__device__ __forceinline__ u16 f2bf(float f) {
    u32 u = __builtin_bit_cast(u32, f);
    u += 0x7fffu + ((u >> 16) & 1u);   // RNE
    return (u16)(u >> 16);
}
// fast tanh-gelu via v_exp (no libm tanhf in the epilogue)
__device__ __forceinline__ float gelu_f(float x) {
    const float u = 0.7978845608028654f * (x + 0.044715f * x * x * x);
    const float e = __expf(-2.f * fabsf(u));
    const float t = __builtin_copysignf((1.f - e) / (1.f + e), u);
    return 0.5f * x * (1.f + t);
}
// async global->LDS DMA, 16 B per lane; LDS dest must be wave-uniform base (m97 path)
__device__ __forceinline__ void glds16(const u16* g, u16* l) {
    __builtin_amdgcn_global_load_lds((const __attribute__((address_space(1))) u32*)g,
                                     (__attribute__((address_space(3))) u32*)l, 16, 0, 0);
}

// ---------------------------------------------------------------- dtype sniff
__global__ void sniff_kernel(const u32* __restrict__ p, int* __restrict__ flag) {
    const int i = threadIdx.x;                    // 0..63
    const u32 w = p[i * 8191 + 5];
    const u32 e = (w >> 7) & 0xFF;
    const bool absurd = (e >= 1 && e <= 90) || (e >= 160 && e <= 254);
    const unsigned long long m = __ballot(absurd);
    if (i == 0) *flag = (__popcll(m) >= 8) ? 1 : 0;
}

// ---------------------------------------------------------------- batched convert
struct CvtPack {
    const void* src[15];
    u16*        dst[15];
    int         n[15];
};
__global__ __launch_bounds__(256) void cvt_many(CvtPack pp, const int* __restrict__ flag) {
    const int f = *flag;
    const int j = blockIdx.y;
    const void* src = pp.src[j];
    u16* dst = pp.dst[j];
    const int n = pp.n[j];
    const int idx = blockIdx.x * 256 + threadIdx.x;
    const int stride = gridDim.x * 256;
    if (f) {
        const float* s = (const float*)src;
        for (int i = idx; i < n; i += stride) dst[i] = f2bf(s[i]);
    } else {
        const u16* s = (const u16*)src;
        for (int i = idx; i < n; i += stride) dst[i] = s[i];
    }
}

// ---------------------------------------------------------------- transpose+convert
// src[Kd][Nd] (f32 or bf16 per flag) -> dst[Nd][Kd] bf16. grid (Nd/32, Kd/32).
__global__ __launch_bounds__(256) void transpose_cv(const void* __restrict__ src,
                                                    u16* __restrict__ dst,
                                                    int Kd, int Nd,
                                                    const int* __restrict__ flag) {
    const int f = *flag;
    __shared__ u16 t[32][33];
    const int tx = threadIdx.x & 31, ty = threadIdx.x >> 5;   // ty 0..7
    const int x  = blockIdx.x * 32 + tx;
    const int y0 = blockIdx.y * 32;
#pragma unroll
    for (int j = 0; j < 4; ++j) {
        const long idx = (long)(y0 + ty + j * 8) * Nd + x;
        t[ty + j * 8][tx] = f ? f2bf(((const float*)src)[idx]) : ((const u16*)src)[idx];
    }
    __syncthreads();
    const int xo = blockIdx.y * 32 + tx;
#pragma unroll
    for (int j = 0; j < 4; ++j)
        dst[(long)(blockIdx.x * 32 + ty + j * 8) * Kd + xo] = t[tx][ty + j * 8];
}

// ---------------------------------------------------------------- layernorm (in-place, bf16)
__global__ __launch_bounds__(256) void ln_kernel(u16* __restrict__ x,
                                                 const u16* __restrict__ g,
                                                 const u16* __restrict__ bta) {
    const int tid = threadIdx.x;
    u16* p = x + (long)blockIdx.x * 1024;
    float v[4];
    float s = 0.f, s2 = 0.f;
#pragma unroll
    for (int i = 0; i < 4; ++i) {
        v[i] = bf2f(p[tid + i * 256]);
        s += v[i]; s2 += v[i] * v[i];
    }
#pragma unroll
    for (int off = 32; off; off >>= 1) {
        s  += __shfl_xor(s, off, 64);
        s2 += __shfl_xor(s2, off, 64);
    }
    __shared__ float ps[8];
    if ((tid & 63) == 0) { ps[(tid >> 6) * 2] = s; ps[(tid >> 6) * 2 + 1] = s2; }
    __syncthreads();
    s  = ps[0] + ps[2] + ps[4] + ps[6];
    s2 = ps[1] + ps[3] + ps[5] + ps[7];
    const float mu  = s * (1.f / 1024.f);
    const float var = s2 * (1.f / 1024.f) - mu * mu;
    const float rs  = rsqrtf(var + 1e-5f);
#pragma unroll
    for (int i = 0; i < 4; ++i) {
        const int c = tid + i * 256;
        p[c] = f2bf((v[i] - mu) * rs * bf2f(g[c]) + bf2f(bta[c]));
    }
}

// ---------------------------------------------------------------- final layernorm
__global__ __launch_bounds__(256) void ln_out_kernel(const u16* __restrict__ xin,
                                                     const u16* __restrict__ g,
                                                     const u16* __restrict__ bta,
                                                     void* __restrict__ out,
                                                     const int* __restrict__ flag) {
    const int tid = threadIdx.x;
    const u16* p = xin + (long)blockIdx.x * 1024;
    float v[4];
    float s = 0.f, s2 = 0.f;
#pragma unroll
    for (int i = 0; i < 4; ++i) {
        v[i] = bf2f(p[tid + i * 256]);
        s += v[i]; s2 += v[i] * v[i];
    }
#pragma unroll
    for (int off = 32; off; off >>= 1) {
        s  += __shfl_xor(s, off, 64);
        s2 += __shfl_xor(s2, off, 64);
    }
    __shared__ float ps[8];
    if ((tid & 63) == 0) { ps[(tid >> 6) * 2] = s; ps[(tid >> 6) * 2 + 1] = s2; }
    __syncthreads();
    s  = ps[0] + ps[2] + ps[4] + ps[6];
    s2 = ps[1] + ps[3] + ps[5] + ps[7];
    const float mu  = s * (1.f / 1024.f);
    const float var = s2 * (1.f / 1024.f) - mu * mu;
    const float rs  = rsqrtf(var + 1e-5f);
    const int f = *flag;
    if (f) {
        float* o = (float*)out + (long)blockIdx.x * 1024;
#pragma unroll
        for (int i = 0; i < 4; ++i) {
            const int c = tid + i * 256;
            o[c] = (v[i] - mu) * rs * bf2f(g[c]) + bf2f(bta[c]);
        }
    } else {
        u16* o = (u16*)out + (long)blockIdx.x * 1024;
#pragma unroll
        for (int i = 0; i < 4; ++i) {
            const int c = tid + i * 256;
            o[c] = f2bf((v[i] - mu) * rs * bf2f(g[c]) + bf2f(bta[c]));
        }
    }
}

// ---------------------------------------------------------------- GEMM v2 (r4-exact)
// C[M,N] = A[M,K] @ W[K,N] (+bias, +res / gelu), W pre-transposed Bt[N,K].
// BM x BN tile, BK=64, 8 waves (512 thr), wave grid 2(M) x 4(N).
// Double-buffered global_load_lds with XOR-swizzled layout (pre-swizzled global
// source, swizzled ds_read) -> conflict-free at 128 B rows. One barrier/K-step.
// rule #19 (confirmed r5-r7): the instantiation SET perturbs codegen; the
// <128,64> siblings doubled the fc dispatch. Instantiation set is pinned to
// {256x256, 128x128, 128x256} - do not add variants without re-benching fc.
template <int BM, int BN, int EPI>    // EPI: 0 = bias, 1 = bias+residual, 2 = bias+gelu
__global__ __launch_bounds__(512, (BM + BN) <= 256 ? 4 : 2)
void gemm2(const u16* __restrict__ A, const u16* __restrict__ Bt,
           const u16* __restrict__ bias, const u16* __restrict__ res,
           u16* __restrict__ C, int N, int K) {
    constexpr int WM  = BM / 2, WN = BN / 4;       // per-wave output tile
    constexpr int MT  = WM / 16, NT = WN / 16;     // 16x16 fragments per wave
    constexpr int ACH = BM / 8;                    // 8-row DMA chunks in A
    constexpr int NCH = (BM + BN) / 8;             // total chunks per K-step
    constexpr int CPW = NCH / 8;                   // chunks per wave
    constexpr int BUF = (BM + BN) * 64;            // u16 elems per LDS buffer

    const int tid  = threadIdx.x;
    const int wave = tid >> 6, lane = tid & 63;
    const int quad = lane >> 4, l16 = lane & 15;
    const int wm = wave >> 2, wn = wave & 3;

    // bijective XCD-aware block swizzle (all grids are %8==0)
    const int gx  = gridDim.x;
    const int nwg = gx * gridDim.y;
    int lin = blockIdx.y * gx + blockIdx.x;
    lin = (lin & 7) * (nwg >> 3) + (lin >> 3);
    const int bx = lin % gx, by = lin / gx;
    const long m0 = (long)by * BM;
    const int  n0 = bx * BN;

    __shared__ u16 L[2][BUF];   // [A rows BM x 64 | B rows BN x 64], swizzled

    f32x4 acc[MT][NT];
#pragma unroll
    for (int i = 0; i < MT; ++i)
#pragma unroll
        for (int j = 0; j < NT; ++j) acc[i][j] = (f32x4){0.f, 0.f, 0.f, 0.f};

    // DMA chunk = 8 rows x 64 k = 1024 B. lane l -> row (l>>3), k-unit (l&7)^((l>>3)&7)
    const int ro   = lane >> 3;
    const int swzk = ((lane & 7) ^ (ro & 7)) << 3;   // pre-swizzled global k offset (elems)
    const u16* gsrc[CPW];
    u16*       ldst[CPW];
#pragma unroll
    for (int c = 0; c < CPW; ++c) {
        const int ch = wave + c * 8;
        const u16* base = (ch < ACH) ? A : Bt;
        const long grow = (ch < ACH) ? (m0 + ch * 8 + ro)
                                     : ((long)n0 + (ch - ACH) * 8 + ro);
        gsrc[c] = base + grow * K + swzk;
        ldst[c] = (u16*)&L[0][ch * 512];
    }

    auto stage = [&](int ib, int kt) {
#pragma unroll
        for (int c = 0; c < CPW; ++c)
            glds16(gsrc[c] + kt, ldst[c] + ib * BUF);
    };

    const int nk = K >> 6;
    stage(0, 0);
    for (int i = 0; i < nk; ++i) {
        const int ib = i & 1;
        __syncthreads();                 // drains vmcnt: buf[ib] staged; prev reads done
        if (i + 1 < nk) stage(ib ^ 1, (i + 1) << 6);
#pragma unroll
        for (int st = 0; st < 2; ++st) {
            bf16x8 af[MT], bfv[NT];
#pragma unroll
            for (int mt = 0; mt < MT; ++mt) {
                const int rr = wm * WM + mt * 16 + l16;
                af[mt] = *(const bf16x8*)&L[ib][rr * 64 + (((st * 4 + quad) ^ (rr & 7)) << 3)];
            }
#pragma unroll
            for (int nt = 0; nt < NT; ++nt) {
                const int rr = wn * WN + nt * 16 + l16;
                bfv[nt] = *(const bf16x8*)&L[ib][BM * 64 + rr * 64 +
                                                 (((st * 4 + quad) ^ (rr & 7)) << 3)];
            }
            __builtin_amdgcn_s_setprio(1);
#pragma unroll
            for (int mt = 0; mt < MT; ++mt)
#pragma unroll
                for (int nt = 0; nt < NT; ++nt)
                    acc[mt][nt] = __builtin_amdgcn_mfma_f32_16x16x32_bf16(af[mt], bfv[nt],
                                                                          acc[mt][nt], 0, 0, 0);
            __builtin_amdgcn_s_setprio(0);
        }
    }

    // D row = quad*4+r, col = l16 (m89/m91-verified)
#pragma unroll
    for (int mt = 0; mt < MT; ++mt)
#pragma unroll
        for (int r = 0; r < 4; ++r) {
            const long row = m0 + wm * WM + mt * 16 + quad * 4 + r;
#pragma unroll
            for (int nt = 0; nt < NT; ++nt) {
                const int col = n0 + wn * WN + nt * 16 + l16;
                float v = acc[mt][nt][r] + bf2f(bias[col]);
                if constexpr (EPI == 1) v += bf2f(res[row * N + col]);
                if constexpr (EPI == 2) v = gelu_f(v);
                C[row * N + col] = f2bf(v);
            }
        }
}

// ---------------------------------------------------------------- attention v4b
// r4 structure: causal pairing {bx, QT-1-bx} REQUIRES grid.x = QT/2 (=8).
// r8 bug: launched with grid.x=16 -> every tile computed twice AND blocks
// bx>=8 violated myn<=nkt (truncated-softmax race, absmax 0.0625->0.0703,
// WRITE doubled). Fixed by grid, kernel unchanged from r8:
// gated cross-lane max-reduce (shuffles only on firing tiles; lane-local max
// + __any is the same predicate as the full reduce).
#define KSTR 72   // 64 + 8 pad (rows stay 16B-aligned: 144 B)
#define MASKV -3.0e4f
template <bool CAUSAL>
__global__ __launch_bounds__(512) void attn3(const u16* __restrict__ Qb,
                                             const u16* __restrict__ Kb,
                                             const u16* __restrict__ Vb,
                                             u16* __restrict__ Ob,
                                             int qstride, int kvstride, int S) {
    const int tid  = threadIdx.x;
    const int wave = tid >> 6, lane = tid & 63;
    const int quad = lane >> 4, l16 = lane & 15;
    const int h = blockIdx.y, b = blockIdx.z;
    const long tokbase = (long)b * S;
    const int QT = S >> 6;

    int qtile;
    if (CAUSAL) qtile = (wave < 4) ? blockIdx.x : (QT - 1 - blockIdx.x);
    else        qtile = blockIdx.x * 2 + (wave >> 2);
    const int qbase = qtile * 64 + (wave & 3) * 16;       // wave's absolute q-row base
    const int nkt = CAUSAL ? (QT - blockIdx.x) : QT;      // tiles staged by block
    const int myn = CAUSAL ? (qtile + 1) : QT;            // tiles this wave computes

    __shared__ u16 K_lds[2][64 * 64];    // XOR-swizzled, 128 B rows
    __shared__ u16 Vt_lds[2][64 * KSTR]; // [d][key], padded rows
    __shared__ u16 P_lds[128 * KSTR];    // [qrow(128)][key], wave-private 16-row bands

    // Q fragments (A-operand: m=l16, k=quad*8+j), pre-scaled by 1/sqrt(64)
    const u16* qrow = Qb + (tokbase + qbase + l16) * qstride + h * 64;
    bf16x8 qf[2];
    qf[0] = *(const bf16x8*)(qrow + quad * 8);
    qf[1] = *(const bf16x8*)(qrow + 32 + quad * 8);
#pragma unroll
    for (int s8 = 0; s8 < 2; ++s8)
#pragma unroll
        for (int j = 0; j < 8; ++j)
            qf[s8][j] = (short)f2bf(bf2f((u16)qf[s8][j]) * 0.125f);   // exact (exp shift)

    f32x4 acc[4];
#pragma unroll
    for (int i = 0; i < 4; ++i) acc[i] = (f32x4){0.f, 0.f, 0.f, 0.f};
    float mrow[4], lsum[4];
#pragma unroll
    for (int r = 0; r < 4; ++r) { mrow[r] = MASKV; lsum[r] = 0.f; }

    // K staging: wave chunk = rows wave*8..wave*8+7 (1024 B linear in LDS).
    // Pre-swizzled global k-offset so linear DMA lands XOR-swizzled (rule #21).
    const int kro = lane >> 3;                       // row within chunk (0..7)
    const int ksw = ((lane & 7) ^ kro) << 3;         // swizzled k elem offset
    const u16* Kln = Kb + (tokbase + wave * 8 + kro) * kvstride + h * 64 + ksw;
    // V staging: thread t -> column d = t&63, keys vkg*8..vkg*8+7
    const int vd = tid & 63, vkg = tid >> 6;
    const u16* Vln = Vb + (tokbase + vkg * 8) * kvstride + h * 64 + vd;

    u16x8 vreg;
    auto loadV = [&](int kt) {
#pragma unroll
        for (int jj = 0; jj < 8; ++jj)
            vreg[jj] = Vln[((long)kt * 64 + jj) * kvstride];
    };

    // prologue: stage tile 0
    loadV(0);
    glds16(Kln, &K_lds[0][wave * 512]);
    *(u16x8*)(&Vt_lds[0][vd * KSTR + vkg * 8]) = vreg;
    __syncthreads();    // drains glds + V writes

    for (int kt = 0; kt < nkt; ++kt) {
        const int cur = kt & 1;
        const bool haveNext = (kt + 1 < nkt);
        if (haveNext) {   // issue next tile's loads early (hide under compute)
            glds16(Kln + (long)(kt + 1) * 64 * kvstride, &K_lds[cur ^ 1][wave * 512]);
            loadV(kt + 1);
        }
        if (kt < myn) {
            // QK^T (pre-scaled): D row(q) = quad*4+r, col(key) = l16
            float p[4][4];
#pragma unroll
            for (int nt = 0; nt < 4; ++nt) {
                f32x4 s = (f32x4){0.f, 0.f, 0.f, 0.f};
#pragma unroll
                for (int st = 0; st < 2; ++st) {
                    bf16x8 kf = *(const bf16x8*)(&K_lds[cur][(nt * 16 + l16) * 64 +
                                                  (((st * 4 + quad) ^ (l16 & 7)) << 3)]);
                    s = __builtin_amdgcn_mfma_f32_16x16x32_bf16(qf[st], kf, s, 0, 0, 0);
                }
#pragma unroll
                for (int r = 0; r < 4; ++r) p[nt][r] = s[r];
            }
            // causal mask: only the diagonal tile needs it (wave-uniform branch)
            if (CAUSAL && kt == qtile) {
#pragma unroll
                for (int nt = 0; nt < 4; ++nt)
#pragma unroll
                    for (int r = 0; r < 4; ++r) {
                        const int qg  = qbase + quad * 4 + r;
                        const int kgi = kt * 64 + nt * 16 + l16;
                        if (kgi > qg) p[nt][r] = MASKV;
                    }
            }
            // online softmax, defer-max (THR=8), GATED cross-lane reduce:
            // lane-local max decides; shuffles only on the (rare) firing tile.
            float lmax[4];
#pragma unroll
            for (int r = 0; r < 4; ++r)
                lmax[r] = fmaxf(fmaxf(p[0][r], p[1][r]), fmaxf(p[2][r], p[3][r]));
            bool need = false;
#pragma unroll
            for (int r = 0; r < 4; ++r) need |= (lmax[r] > mrow[r] + 8.f);
            if (__any(need)) {   // wave-uniform: full reduce + rescale
#pragma unroll
                for (int r = 0; r < 4; ++r) {
                    float m3 = lmax[r];
#pragma unroll
                    for (int off = 1; off <= 8; off <<= 1)
                        m3 = fmaxf(m3, __shfl_xor(m3, off, 64));
                    const float newm  = fmaxf(mrow[r], m3);
                    const float alpha = __expf(mrow[r] - newm);
                    mrow[r] = newm;
                    lsum[r] *= alpha;
#pragma unroll
                    for (int dt = 0; dt < 4; ++dt) acc[dt][r] *= alpha;
                }
            }
#pragma unroll
            for (int nt = 0; nt < 4; ++nt)
#pragma unroll
                for (int r = 0; r < 4; ++r) {
                    p[nt][r] = __expf(p[nt][r] - mrow[r]);   // bounded by e^8
                    lsum[r] += p[nt][r];                     // per-lane partial (deferred)
                }
            // P -> LDS (wave-private rows; PV below needs only lgkmcnt, no barrier)
#pragma unroll
            for (int nt = 0; nt < 4; ++nt)
#pragma unroll
                for (int r = 0; r < 4; ++r)
                    P_lds[(wave * 16 + quad * 4 + r) * KSTR + nt * 16 + l16] = f2bf(p[nt][r]);
            // PV: O[q][d] += P[q][key] * Vt[d][key]
#pragma unroll
            for (int st = 0; st < 2; ++st) {
                bf16x8 pf = *(const bf16x8*)(&P_lds[(wave * 16 + l16) * KSTR + st * 32 + quad * 8]);
#pragma unroll
                for (int dt = 0; dt < 4; ++dt) {
                    bf16x8 vf = *(const bf16x8*)(&Vt_lds[cur][(dt * 16 + l16) * KSTR +
                                                              st * 32 + quad * 8]);
                    acc[dt] = __builtin_amdgcn_mfma_f32_16x16x32_bf16(pf, vf, acc[dt], 0, 0, 0);
                }
            }
        }
        if (haveNext)   // write-late: V regs -> next buffer (vmcnt wait by compiler)
            *(u16x8*)(&Vt_lds[cur ^ 1][vd * KSTR + vkg * 8]) = vreg;
        __syncthreads();   // one barrier/tile: drains next-tile glds, publishes Vt
    }

#pragma unroll
    for (int r = 0; r < 4; ++r) {
        float rs = lsum[r];    // epilogue cross-lane sum reduce (deferred from loop)
#pragma unroll
        for (int off = 1; off <= 8; off <<= 1) rs += __shfl_xor(rs, off, 64);
        const float inv = 1.f / rs;
        const long row = tokbase + qbase + quad * 4 + r;
#pragma unroll
        for (int dt = 0; dt < 4; ++dt)
            Ob[row * 1024 + h * 64 + dt * 16 + l16] = f2bf(acc[dt][r] * inv);
    }
}

// ---------------------------------------------------------------- launch
extern "C" void kernel_launch(void* const* d_in, const int* in_sizes, int n_in,
                              void* d_out, int out_size, void* d_ws, size_t ws_size,
                              hipStream_t stream) {
    u16* ws = (u16*)d_ws;
    // ---- workspace layout (u16 elements) ----
    u16* Wt_attn  = ws + 0;          // 3072x1024
    u16* Wt_self  = ws + 3145728;    // 1024x1024
    u16* Wt_q     = ws + 4194304;    // 1024x1024
    u16* Wt_kv    = ws + 5242880;    // 2048x1024
    u16* Wt_cross = ws + 7340032;    // 1024x1024
    u16* Wt_fc    = ws + 8388608;    // 4096x1024
    u16* Wt_mlp   = ws + 12582912;   // 1024x4096 (ends 16777216)
    u16* qkv      = ws + 16777216;   // 4096x3072 (dead after self-attn)
    u16* q2       = ws + 16777216;   // 4096x1024 (reuse)
    u16* kv2      = ws + 20971520;   // 4096x2048 (reuse)
    u16* x2       = ws + 16777216;   // 4096x1024 (reuse; live into MLP)
    u16* hbuf     = ws + 20971520;   // 4096x4096 (reuse; ends 37748736)
    u16* abuf     = ws + 29360128;   // 4096x1024
    u16* x1       = ws + 33554432;   // 4096x1024 (ends 37748736)
    u16* xb       = ws + 37748736;   // 4096x1024 (converted x; dead after self-proj)
    u16* y3       = ws + 37748736;   // 4096x1024 (MLP out pre-LN; reuses xb slot)
    u16* ctxb     = ws + 41943040;   // 4096x1024 (converted ctx)
    u16* P        = ws + 46137344;   // param slots
    u16* cab = P;            u16* spb = P + 4096;  u16* qb  = P + 8192;
    u16* kvb = P + 12288;    u16* cpb = P + 16384; u16* fcb = P + 20480;
    u16* mpb = P + 24576;
    u16* l1g = P + 28672;  u16* l1b = P + 32768;
    u16* l2g = P + 36864;  u16* l2b = P + 40960;
    u16* l3g = P + 45056;  u16* l3b = P + 49152;
    int* flag = (int*)(ws + 46137344 + 53248);

    const dim3 tb(256);
    const dim3 tg(512);
    const int NTOK = 4096;

    // ---- dtype sniff on x ----
    sniff_kernel<<<1, 64, 0, stream>>>((const u32*)d_in[0], flag);

    // ---- convert activations + params to bf16 (single batched launch) ----
    CvtPack pp;
    pp.src[0] = d_in[0];  pp.dst[0] = xb;   pp.n[0] = NTOK * 1024;
    pp.src[1] = d_in[1];  pp.dst[1] = ctxb; pp.n[1] = NTOK * 1024;
    pp.src[2] = d_in[3];  pp.dst[2] = cab;  pp.n[2] = 3072;
    pp.src[3] = d_in[5];  pp.dst[3] = spb;  pp.n[3] = 1024;
    pp.src[4] = d_in[7];  pp.dst[4] = qb;   pp.n[4] = 1024;
    pp.src[5] = d_in[9];  pp.dst[5] = kvb;  pp.n[5] = 2048;
    pp.src[6] = d_in[11]; pp.dst[6] = cpb;  pp.n[6] = 1024;
    pp.src[7] = d_in[13]; pp.dst[7] = fcb;  pp.n[7] = 4096;
    pp.src[8] = d_in[15]; pp.dst[8] = mpb;  pp.n[8] = 1024;
    pp.src[9] = d_in[16]; pp.dst[9] = l1g;  pp.n[9] = 1024;
    pp.src[10] = d_in[17]; pp.dst[10] = l1b; pp.n[10] = 1024;
    pp.src[11] = d_in[18]; pp.dst[11] = l2g; pp.n[11] = 1024;
    pp.src[12] = d_in[19]; pp.dst[12] = l2b; pp.n[12] = 1024;
    pp.src[13] = d_in[20]; pp.dst[13] = l3g; pp.n[13] = 1024;
    pp.src[14] = d_in[21]; pp.dst[14] = l3b; pp.n[14] = 1024;
    cvt_many<<<dim3(256, 15), tb, 0, stream>>>(pp, flag);

    // ---- weight transposes (+convert): W[K,N] -> Wt[N,K] ----
    transpose_cv<<<dim3(96, 32),  tb, 0, stream>>>(d_in[2],  Wt_attn,  1024, 3072, flag);
    transpose_cv<<<dim3(32, 32),  tb, 0, stream>>>(d_in[4],  Wt_self,  1024, 1024, flag);
    transpose_cv<<<dim3(32, 32),  tb, 0, stream>>>(d_in[6],  Wt_q,     1024, 1024, flag);
    transpose_cv<<<dim3(64, 32),  tb, 0, stream>>>(d_in[8],  Wt_kv,    1024, 2048, flag);
    transpose_cv<<<dim3(32, 32),  tb, 0, stream>>>(d_in[10], Wt_cross, 1024, 1024, flag);
    transpose_cv<<<dim3(128, 32), tb, 0, stream>>>(d_in[12], Wt_fc,    1024, 4096, flag);
    transpose_cv<<<dim3(32, 128), tb, 0, stream>>>(d_in[14], Wt_mlp,   4096, 1024, flag);

    // --- causal self-attention ---
    gemm2<256, 256, 0><<<dim3(12, 16), tg, 0, stream>>>(xb, Wt_attn, cab, nullptr, qkv, 3072, 1024);
    attn3<true><<<dim3(8, 16, 4), tg, 0, stream>>>(qkv, qkv + 1024, qkv + 2048, abuf,
                                                   3072, 3072, 1024);
    gemm2<128, 128, 1><<<dim3(8, 32), tg, 0, stream>>>(abuf, Wt_self, spb, xb, x1, 1024, 1024);
    ln_kernel<<<NTOK, tb, 0, stream>>>(x1, l1g, l1b);

    // --- cross-attention ---
    gemm2<128, 128, 0><<<dim3(8, 32),  tg, 0, stream>>>(x1,   Wt_q,  qb,  nullptr, q2,  1024, 1024);
    gemm2<128, 256, 0><<<dim3(8, 32), tg, 0, stream>>>(ctxb, Wt_kv, kvb, nullptr, kv2, 2048, 1024);
    attn3<false><<<dim3(8, 16, 4), tg, 0, stream>>>(q2, kv2, kv2 + 1024, abuf,
                                                    1024, 2048, 1024);
    gemm2<128, 128, 1><<<dim3(8, 32), tg, 0, stream>>>(abuf, Wt_cross, cpb, x1, x2, 1024, 1024);
    ln_kernel<<<NTOK, tb, 0, stream>>>(x2, l2g, l2b);

    // --- MLP ---
    gemm2<256, 256, 2><<<dim3(16, 16), tg, 0, stream>>>(x2, Wt_fc, fcb, nullptr, hbuf, 4096, 1024);
    gemm2<128, 128, 1><<<dim3(8, 32), tg, 0, stream>>>(hbuf, Wt_mlp, mpb, x2, y3, 1024, 4096);
    ln_out_kernel<<<NTOK, tb, 0, stream>>>(y3, l3g, l3b, d_out, flag);
}

// Round 10
// 485.118 us; speedup vs baseline: 1.0591x; 1.0184x over previous
//
#include <hip/hip_runtime.h>

typedef unsigned short u16;
typedef unsigned int   u32;
typedef short bf16x8 __attribute__((ext_vector_type(8)));   // 8 bf16 (4 VGPRs)
typedef unsigned short u16x8 __attribute__((ext_vector_type(8)));
typedef float f32x4 __attribute__((ext_vector_type(4)));

__device__ __forceinline__ float bf2f(u16 u) {
    u32 x = ((u32)u) << 16;
    return __builtin_bit_cast(float, x);
}
__device__ __forceinline__ u16 f2bf(float f) {
    u32 u = __builtin_bit_cast(u32, f);
    u += 0x7fffu + ((u >> 16) & 1u);   // RNE
    return (u16)(u >> 16);
}
// fast tanh-gelu via v_exp (no libm tanhf in the epilogue)
__device__ __forceinline__ float gelu_f(float x) {
    const float u = 0.7978845608028654f * (x + 0.044715f * x * x * x);
    const float e = __expf(-2.f * fabsf(u));
    const float t = __builtin_copysignf((1.f - e) / (1.f + e), u);
    return 0.5f * x * (1.f + t);
}
// async global->LDS DMA, 16 B per lane; LDS dest must be wave-uniform base (m97 path)
__device__ __forceinline__ void glds16(const u16* g, u16* l) {
    __builtin_amdgcn_global_load_lds((const __attribute__((address_space(1))) u32*)g,
                                     (__attribute__((address_space(3))) u32*)l, 16, 0, 0);
}

// ---------------------------------------------------------------- dtype sniff
__global__ void sniff_kernel(const u32* __restrict__ p, int* __restrict__ flag) {
    const int i = threadIdx.x;                    // 0..63
    const u32 w = p[i * 8191 + 5];
    const u32 e = (w >> 7) & 0xFF;
    const bool absurd = (e >= 1 && e <= 90) || (e >= 160 && e <= 254);
    const unsigned long long m = __ballot(absurd);
    if (i == 0) *flag = (__popcll(m) >= 8) ? 1 : 0;
}

// ---------------------------------------------------------------- batched convert
struct CvtPack {
    const void* src[15];
    u16*        dst[15];
    int         n[15];
};
__global__ __launch_bounds__(256) void cvt_many(CvtPack pp, const int* __restrict__ flag) {
    const int f = *flag;
    const int j = blockIdx.y;
    const void* src = pp.src[j];
    u16* dst = pp.dst[j];
    const int n = pp.n[j];
    const int idx = blockIdx.x * 256 + threadIdx.x;
    const int stride = gridDim.x * 256;
    if (f) {
        const float* s = (const float*)src;
        for (int i = idx; i < n; i += stride) dst[i] = f2bf(s[i]);
    } else {
        const u16* s = (const u16*)src;
        for (int i = idx; i < n; i += stride) dst[i] = s[i];
    }
}

// ---------------------------------------------------------------- transpose+convert
// src[Kd][Nd] (f32 or bf16 per flag) -> dst[Nd][Kd] bf16. grid (Nd/32, Kd/32).
__global__ __launch_bounds__(256) void transpose_cv(const void* __restrict__ src,
                                                    u16* __restrict__ dst,
                                                    int Kd, int Nd,
                                                    const int* __restrict__ flag) {
    const int f = *flag;
    __shared__ u16 t[32][33];
    const int tx = threadIdx.x & 31, ty = threadIdx.x >> 5;   // ty 0..7
    const int x  = blockIdx.x * 32 + tx;
    const int y0 = blockIdx.y * 32;
#pragma unroll
    for (int j = 0; j < 4; ++j) {
        const long idx = (long)(y0 + ty + j * 8) * Nd + x;
        t[ty + j * 8][tx] = f ? f2bf(((const float*)src)[idx]) : ((const u16*)src)[idx];
    }
    __syncthreads();
    const int xo = blockIdx.y * 32 + tx;
#pragma unroll
    for (int j = 0; j < 4; ++j)
        dst[(long)(blockIdx.x * 32 + ty + j * 8) * Kd + xo] = t[tx][ty + j * 8];
}

// ---------------------------------------------------------------- layernorm (in-place, bf16)
__global__ __launch_bounds__(256) void ln_kernel(u16* __restrict__ x,
                                                 const u16* __restrict__ g,
                                                 const u16* __restrict__ bta) {
    const int tid = threadIdx.x;
    u16* p = x + (long)blockIdx.x * 1024;
    float v[4];
    float s = 0.f, s2 = 0.f;
#pragma unroll
    for (int i = 0; i < 4; ++i) {
        v[i] = bf2f(p[tid + i * 256]);
        s += v[i]; s2 += v[i] * v[i];
    }
#pragma unroll
    for (int off = 32; off; off >>= 1) {
        s  += __shfl_xor(s, off, 64);
        s2 += __shfl_xor(s2, off, 64);
    }
    __shared__ float ps[8];
    if ((tid & 63) == 0) { ps[(tid >> 6) * 2] = s; ps[(tid >> 6) * 2 + 1] = s2; }
    __syncthreads();
    s  = ps[0] + ps[2] + ps[4] + ps[6];
    s2 = ps[1] + ps[3] + ps[5] + ps[7];
    const float mu  = s * (1.f / 1024.f);
    const float var = s2 * (1.f / 1024.f) - mu * mu;
    const float rs  = rsqrtf(var + 1e-5f);
#pragma unroll
    for (int i = 0; i < 4; ++i) {
        const int c = tid + i * 256;
        p[c] = f2bf((v[i] - mu) * rs * bf2f(g[c]) + bf2f(bta[c]));
    }
}

// ---------------------------------------------------------------- final layernorm
__global__ __launch_bounds__(256) void ln_out_kernel(const u16* __restrict__ xin,
                                                     const u16* __restrict__ g,
                                                     const u16* __restrict__ bta,
                                                     void* __restrict__ out,
                                                     const int* __restrict__ flag) {
    const int tid = threadIdx.x;
    const u16* p = xin + (long)blockIdx.x * 1024;
    float v[4];
    float s = 0.f, s2 = 0.f;
#pragma unroll
    for (int i = 0; i < 4; ++i) {
        v[i] = bf2f(p[tid + i * 256]);
        s += v[i]; s2 += v[i] * v[i];
    }
#pragma unroll
    for (int off = 32; off; off >>= 1) {
        s  += __shfl_xor(s, off, 64);
        s2 += __shfl_xor(s2, off, 64);
    }
    __shared__ float ps[8];
    if ((tid & 63) == 0) { ps[(tid >> 6) * 2] = s; ps[(tid >> 6) * 2 + 1] = s2; }
    __syncthreads();
    s  = ps[0] + ps[2] + ps[4] + ps[6];
    s2 = ps[1] + ps[3] + ps[5] + ps[7];
    const float mu  = s * (1.f / 1024.f);
    const float var = s2 * (1.f / 1024.f) - mu * mu;
    const float rs  = rsqrtf(var + 1e-5f);
    const int f = *flag;
    if (f) {
        float* o = (float*)out + (long)blockIdx.x * 1024;
#pragma unroll
        for (int i = 0; i < 4; ++i) {
            const int c = tid + i * 256;
            o[c] = (v[i] - mu) * rs * bf2f(g[c]) + bf2f(bta[c]);
        }
    } else {
        u16* o = (u16*)out + (long)blockIdx.x * 1024;
#pragma unroll
        for (int i = 0; i < 4; ++i) {
            const int c = tid + i * 256;
            o[c] = f2bf((v[i] - mu) * rs * bf2f(g[c]) + bf2f(bta[c]));
        }
    }
}

// ---------------------------------------------------------------- GEMM v2 (128-tile family)
// C[M,N] = A[M,K] @ W[K,N] (+bias, +res / gelu), W pre-transposed Bt[N,K].
// BM x BN tile, BK=64, 8 waves (512 thr), wave grid 2(M) x 4(N).
// Double-buffered global_load_lds with XOR-swizzled layout (pre-swizzled global
// source, swizzled ds_read) -> conflict-free at 128 B rows. One barrier/K-step.
// rule #19 (confirmed r5-r9): sibling edits in this TU flip the 256x256
// instantiation between 55us and 95us modes. The 256x256 tiles now live in
// their OWN template (gemm_big below) to decouple codegen contexts; gemm2 is
// instantiated ONLY at {128x128(0), 128x128(1), 128x256(0)}.
template <int BM, int BN, int EPI>    // EPI: 0 = bias, 1 = bias+residual, 2 = bias+gelu
__global__ __launch_bounds__(512, (BM + BN) <= 256 ? 4 : 2)
void gemm2(const u16* __restrict__ A, const u16* __restrict__ Bt,
           const u16* __restrict__ bias, const u16* __restrict__ res,
           u16* __restrict__ C, int N, int K) {
    constexpr int WM  = BM / 2, WN = BN / 4;       // per-wave output tile
    constexpr int MT  = WM / 16, NT = WN / 16;     // 16x16 fragments per wave
    constexpr int ACH = BM / 8;                    // 8-row DMA chunks in A
    constexpr int NCH = (BM + BN) / 8;             // total chunks per K-step
    constexpr int CPW = NCH / 8;                   // chunks per wave
    constexpr int BUF = (BM + BN) * 64;            // u16 elems per LDS buffer

    const int tid  = threadIdx.x;
    const int wave = tid >> 6, lane = tid & 63;
    const int quad = lane >> 4, l16 = lane & 15;
    const int wm = wave >> 2, wn = wave & 3;

    // bijective XCD-aware block swizzle (all grids are %8==0)
    const int gx  = gridDim.x;
    const int nwg = gx * gridDim.y;
    int lin = blockIdx.y * gx + blockIdx.x;
    lin = (lin & 7) * (nwg >> 3) + (lin >> 3);
    const int bx = lin % gx, by = lin / gx;
    const long m0 = (long)by * BM;
    const int  n0 = bx * BN;

    __shared__ u16 L[2][BUF];   // [A rows BM x 64 | B rows BN x 64], swizzled

    f32x4 acc[MT][NT];
#pragma unroll
    for (int i = 0; i < MT; ++i)
#pragma unroll
        for (int j = 0; j < NT; ++j) acc[i][j] = (f32x4){0.f, 0.f, 0.f, 0.f};

    // DMA chunk = 8 rows x 64 k = 1024 B. lane l -> row (l>>3), k-unit (l&7)^((l>>3)&7)
    const int ro   = lane >> 3;
    const int swzk = ((lane & 7) ^ (ro & 7)) << 3;   // pre-swizzled global k offset (elems)
    const u16* gsrc[CPW];
    u16*       ldst[CPW];
#pragma unroll
    for (int c = 0; c < CPW; ++c) {
        const int ch = wave + c * 8;
        const u16* base = (ch < ACH) ? A : Bt;
        const long grow = (ch < ACH) ? (m0 + ch * 8 + ro)
                                     : ((long)n0 + (ch - ACH) * 8 + ro);
        gsrc[c] = base + grow * K + swzk;
        ldst[c] = (u16*)&L[0][ch * 512];
    }

    auto stage = [&](int ib, int kt) {
#pragma unroll
        for (int c = 0; c < CPW; ++c)
            glds16(gsrc[c] + kt, ldst[c] + ib * BUF);
    };

    const int nk = K >> 6;
    stage(0, 0);
    for (int i = 0; i < nk; ++i) {
        const int ib = i & 1;
        __syncthreads();                 // drains vmcnt: buf[ib] staged; prev reads done
        if (i + 1 < nk) stage(ib ^ 1, (i + 1) << 6);
#pragma unroll
        for (int st = 0; st < 2; ++st) {
            bf16x8 af[MT], bfv[NT];
#pragma unroll
            for (int mt = 0; mt < MT; ++mt) {
                const int rr = wm * WM + mt * 16 + l16;
                af[mt] = *(const bf16x8*)&L[ib][rr * 64 + (((st * 4 + quad) ^ (rr & 7)) << 3)];
            }
#pragma unroll
            for (int nt = 0; nt < NT; ++nt) {
                const int rr = wn * WN + nt * 16 + l16;
                bfv[nt] = *(const bf16x8*)&L[ib][BM * 64 + rr * 64 +
                                                 (((st * 4 + quad) ^ (rr & 7)) << 3)];
            }
            __builtin_amdgcn_s_setprio(1);
#pragma unroll
            for (int mt = 0; mt < MT; ++mt)
#pragma unroll
                for (int nt = 0; nt < NT; ++nt)
                    acc[mt][nt] = __builtin_amdgcn_mfma_f32_16x16x32_bf16(af[mt], bfv[nt],
                                                                          acc[mt][nt], 0, 0, 0);
            __builtin_amdgcn_s_setprio(0);
        }
    }

    // D row = quad*4+r, col = l16 (m89/m91-verified)
#pragma unroll
    for (int mt = 0; mt < MT; ++mt)
#pragma unroll
        for (int r = 0; r < 4; ++r) {
            const long row = m0 + wm * WM + mt * 16 + quad * 4 + r;
#pragma unroll
            for (int nt = 0; nt < NT; ++nt) {
                const int col = n0 + wn * WN + nt * 16 + l16;
                float v = acc[mt][nt][r] + bf2f(bias[col]);
                if constexpr (EPI == 1) v += bf2f(res[row * N + col]);
                if constexpr (EPI == 2) v = gelu_f(v);
                C[row * N + col] = f2bf(v);
            }
        }
}

// ---------------------------------------------------------------- GEMM big (256x256 family)
// Byte-identical logic to gemm2<256,256,EPI>, in a SEPARATE template so the
// big-tile instantiations have their own codegen context (rule #19 decoupling
// probe: fc flipped 55us<->95us across rounds purely from TU sibling edits).
template <int EPI>    // 0 = bias, 2 = bias+gelu
__global__ __launch_bounds__(512, 2)
void gemm_big(const u16* __restrict__ A, const u16* __restrict__ Bt,
              const u16* __restrict__ bias, const u16* __restrict__ res,
              u16* __restrict__ C, int N, int K) {
    constexpr int BM = 256, BN = 256;
    constexpr int WM  = BM / 2, WN = BN / 4;       // 128 x 64 per wave
    constexpr int MT  = WM / 16, NT = WN / 16;     // 8 x 4 fragments
    constexpr int ACH = BM / 8;                    // 32 A-chunks
    constexpr int NCH = (BM + BN) / 8;             // 64 chunks per K-step
    constexpr int CPW = NCH / 8;                   // 8 chunks per wave
    constexpr int BUF = (BM + BN) * 64;            // 32768 u16 per buffer

    const int tid  = threadIdx.x;
    const int wave = tid >> 6, lane = tid & 63;
    const int quad = lane >> 4, l16 = lane & 15;
    const int wm = wave >> 2, wn = wave & 3;

    // bijective XCD-aware block swizzle (all grids are %8==0)
    const int gx  = gridDim.x;
    const int nwg = gx * gridDim.y;
    int lin = blockIdx.y * gx + blockIdx.x;
    lin = (lin & 7) * (nwg >> 3) + (lin >> 3);
    const int bx = lin % gx, by = lin / gx;
    const long m0 = (long)by * BM;
    const int  n0 = bx * BN;

    __shared__ u16 L[2][BUF];   // [A rows 256 x 64 | B rows 256 x 64], swizzled

    f32x4 acc[MT][NT];
#pragma unroll
    for (int i = 0; i < MT; ++i)
#pragma unroll
        for (int j = 0; j < NT; ++j) acc[i][j] = (f32x4){0.f, 0.f, 0.f, 0.f};

    // DMA chunk = 8 rows x 64 k = 1024 B. lane l -> row (l>>3), k-unit (l&7)^((l>>3)&7)
    const int ro   = lane >> 3;
    const int swzk = ((lane & 7) ^ (ro & 7)) << 3;   // pre-swizzled global k offset (elems)
    const u16* gsrc[CPW];
    u16*       ldst[CPW];
#pragma unroll
    for (int c = 0; c < CPW; ++c) {
        const int ch = wave + c * 8;
        const u16* base = (ch < ACH) ? A : Bt;
        const long grow = (ch < ACH) ? (m0 + ch * 8 + ro)
                                     : ((long)n0 + (ch - ACH) * 8 + ro);
        gsrc[c] = base + grow * K + swzk;
        ldst[c] = (u16*)&L[0][ch * 512];
    }

    auto stage = [&](int ib, int kt) {
#pragma unroll
        for (int c = 0; c < CPW; ++c)
            glds16(gsrc[c] + kt, ldst[c] + ib * BUF);
    };

    const int nk = K >> 6;
    stage(0, 0);
    for (int i = 0; i < nk; ++i) {
        const int ib = i & 1;
        __syncthreads();                 // drains vmcnt: buf[ib] staged; prev reads done
        if (i + 1 < nk) stage(ib ^ 1, (i + 1) << 6);
#pragma unroll
        for (int st = 0; st < 2; ++st) {
            bf16x8 af[MT], bfv[NT];
#pragma unroll
            for (int mt = 0; mt < MT; ++mt) {
                const int rr = wm * WM + mt * 16 + l16;
                af[mt] = *(const bf16x8*)&L[ib][rr * 64 + (((st * 4 + quad) ^ (rr & 7)) << 3)];
            }
#pragma unroll
            for (int nt = 0; nt < NT; ++nt) {
                const int rr = wn * WN + nt * 16 + l16;
                bfv[nt] = *(const bf16x8*)&L[ib][BM * 64 + rr * 64 +
                                                 (((st * 4 + quad) ^ (rr & 7)) << 3)];
            }
            __builtin_amdgcn_s_setprio(1);
#pragma unroll
            for (int mt = 0; mt < MT; ++mt)
#pragma unroll
                for (int nt = 0; nt < NT; ++nt)
                    acc[mt][nt] = __builtin_amdgcn_mfma_f32_16x16x32_bf16(af[mt], bfv[nt],
                                                                          acc[mt][nt], 0, 0, 0);
            __builtin_amdgcn_s_setprio(0);
        }
    }

    // D row = quad*4+r, col = l16 (m89/m91-verified)
#pragma unroll
    for (int mt = 0; mt < MT; ++mt)
#pragma unroll
        for (int r = 0; r < 4; ++r) {
            const long row = m0 + wm * WM + mt * 16 + quad * 4 + r;
#pragma unroll
            for (int nt = 0; nt < NT; ++nt) {
                const int col = n0 + wn * WN + nt * 16 + l16;
                float v = acc[mt][nt][r] + bf2f(bias[col]);
                if constexpr (EPI == 2) v = gelu_f(v);
                C[row * N + col] = f2bf(v);
            }
        }
}

// ---------------------------------------------------------------- attention v4b (r9-exact)
// 8 waves, 128 q rows (two 64-row tiles: causal {bx, QT-1-bx}, grid.x MUST be
// QT/2). K glds-dbuf + V reg-staged issue-early/write-late, 1 barrier/tile.
// Diagonal-only mask, Q pre-scaled 1/8, deferred per-lane sum, defer-max THR=8
// with GATED cross-lane max-reduce (shuffles only on firing tiles).
#define KSTR 72   // 64 + 8 pad (rows stay 16B-aligned: 144 B)
#define MASKV -3.0e4f
template <bool CAUSAL>
__global__ __launch_bounds__(512) void attn3(const u16* __restrict__ Qb,
                                             const u16* __restrict__ Kb,
                                             const u16* __restrict__ Vb,
                                             u16* __restrict__ Ob,
                                             int qstride, int kvstride, int S) {
    const int tid  = threadIdx.x;
    const int wave = tid >> 6, lane = tid & 63;
    const int quad = lane >> 4, l16 = lane & 15;
    const int h = blockIdx.y, b = blockIdx.z;
    const long tokbase = (long)b * S;
    const int QT = S >> 6;

    int qtile;
    if (CAUSAL) qtile = (wave < 4) ? blockIdx.x : (QT - 1 - blockIdx.x);
    else        qtile = blockIdx.x * 2 + (wave >> 2);
    const int qbase = qtile * 64 + (wave & 3) * 16;       // wave's absolute q-row base
    const int nkt = CAUSAL ? (QT - blockIdx.x) : QT;      // tiles staged by block
    const int myn = CAUSAL ? (qtile + 1) : QT;            // tiles this wave computes

    __shared__ u16 K_lds[2][64 * 64];    // XOR-swizzled, 128 B rows
    __shared__ u16 Vt_lds[2][64 * KSTR]; // [d][key], padded rows
    __shared__ u16 P_lds[128 * KSTR];    // [qrow(128)][key], wave-private 16-row bands

    // Q fragments (A-operand: m=l16, k=quad*8+j), pre-scaled by 1/sqrt(64)
    const u16* qrow = Qb + (tokbase + qbase + l16) * qstride + h * 64;
    bf16x8 qf[2];
    qf[0] = *(const bf16x8*)(qrow + quad * 8);
    qf[1] = *(const bf16x8*)(qrow + 32 + quad * 8);
#pragma unroll
    for (int s8 = 0; s8 < 2; ++s8)
#pragma unroll
        for (int j = 0; j < 8; ++j)
            qf[s8][j] = (short)f2bf(bf2f((u16)qf[s8][j]) * 0.125f);   // exact (exp shift)

    f32x4 acc[4];
#pragma unroll
    for (int i = 0; i < 4; ++i) acc[i] = (f32x4){0.f, 0.f, 0.f, 0.f};
    float mrow[4], lsum[4];
#pragma unroll
    for (int r = 0; r < 4; ++r) { mrow[r] = MASKV; lsum[r] = 0.f; }

    // K staging: wave chunk = rows wave*8..wave*8+7 (1024 B linear in LDS).
    // Pre-swizzled global k-offset so linear DMA lands XOR-swizzled (rule #21).
    const int kro = lane >> 3;                       // row within chunk (0..7)
    const int ksw = ((lane & 7) ^ kro) << 3;         // swizzled k elem offset
    const u16* Kln = Kb + (tokbase + wave * 8 + kro) * kvstride + h * 64 + ksw;
    // V staging: thread t -> column d = t&63, keys vkg*8..vkg*8+7
    const int vd = tid & 63, vkg = tid >> 6;
    const u16* Vln = Vb + (tokbase + vkg * 8) * kvstride + h * 64 + vd;

    u16x8 vreg;
    auto loadV = [&](int kt) {
#pragma unroll
        for (int jj = 0; jj < 8; ++jj)
            vreg[jj] = Vln[((long)kt * 64 + jj) * kvstride];
    };

    // prologue: stage tile 0
    loadV(0);
    glds16(Kln, &K_lds[0][wave * 512]);
    *(u16x8*)(&Vt_lds[0][vd * KSTR + vkg * 8]) = vreg;
    __syncthreads();    // drains glds + V writes

    for (int kt = 0; kt < nkt; ++kt) {
        const int cur = kt & 1;
        const bool haveNext = (kt + 1 < nkt);
        if (haveNext) {   // issue next tile's loads early (hide under compute)
            glds16(Kln + (long)(kt + 1) * 64 * kvstride, &K_lds[cur ^ 1][wave * 512]);
            loadV(kt + 1);
        }
        if (kt < myn) {
            // QK^T (pre-scaled): D row(q) = quad*4+r, col(key) = l16
            float p[4][4];
#pragma unroll
            for (int nt = 0; nt < 4; ++nt) {
                f32x4 s = (f32x4){0.f, 0.f, 0.f, 0.f};
#pragma unroll
                for (int st = 0; st < 2; ++st) {
                    bf16x8 kf = *(const bf16x8*)(&K_lds[cur][(nt * 16 + l16) * 64 +
                                                  (((st * 4 + quad) ^ (l16 & 7)) << 3)]);
                    s = __builtin_amdgcn_mfma_f32_16x16x32_bf16(qf[st], kf, s, 0, 0, 0);
                }
#pragma unroll
                for (int r = 0; r < 4; ++r) p[nt][r] = s[r];
            }
            // causal mask: only the diagonal tile needs it (wave-uniform branch)
            if (CAUSAL && kt == qtile) {
#pragma unroll
                for (int nt = 0; nt < 4; ++nt)
#pragma unroll
                    for (int r = 0; r < 4; ++r) {
                        const int qg  = qbase + quad * 4 + r;
                        const int kgi = kt * 64 + nt * 16 + l16;
                        if (kgi > qg) p[nt][r] = MASKV;
                    }
            }
            // online softmax, defer-max (THR=8), GATED cross-lane reduce:
            // lane-local max decides; shuffles only on the (rare) firing tile.
            float lmax[4];
#pragma unroll
            for (int r = 0; r < 4; ++r)
                lmax[r] = fmaxf(fmaxf(p[0][r], p[1][r]), fmaxf(p[2][r], p[3][r]));
            bool need = false;
#pragma unroll
            for (int r = 0; r < 4; ++r) need |= (lmax[r] > mrow[r] + 8.f);
            if (__any(need)) {   // wave-uniform: full reduce + rescale
#pragma unroll
                for (int r = 0; r < 4; ++r) {
                    float m3 = lmax[r];
#pragma unroll
                    for (int off = 1; off <= 8; off <<= 1)
                        m3 = fmaxf(m3, __shfl_xor(m3, off, 64));
                    const float newm  = fmaxf(mrow[r], m3);
                    const float alpha = __expf(mrow[r] - newm);
                    mrow[r] = newm;
                    lsum[r] *= alpha;
#pragma unroll
                    for (int dt = 0; dt < 4; ++dt) acc[dt][r] *= alpha;
                }
            }
#pragma unroll
            for (int nt = 0; nt < 4; ++nt)
#pragma unroll
                for (int r = 0; r < 4; ++r) {
                    p[nt][r] = __expf(p[nt][r] - mrow[r]);   // bounded by e^8
                    lsum[r] += p[nt][r];                     // per-lane partial (deferred)
                }
            // P -> LDS (wave-private rows; PV below needs only lgkmcnt, no barrier)
#pragma unroll
            for (int nt = 0; nt < 4; ++nt)
#pragma unroll
                for (int r = 0; r < 4; ++r)
                    P_lds[(wave * 16 + quad * 4 + r) * KSTR + nt * 16 + l16] = f2bf(p[nt][r]);
            // PV: O[q][d] += P[q][key] * Vt[d][key]
#pragma unroll
            for (int st = 0; st < 2; ++st) {
                bf16x8 pf = *(const bf16x8*)(&P_lds[(wave * 16 + l16) * KSTR + st * 32 + quad * 8]);
#pragma unroll
                for (int dt = 0; dt < 4; ++dt) {
                    bf16x8 vf = *(const bf16x8*)(&Vt_lds[cur][(dt * 16 + l16) * KSTR +
                                                              st * 32 + quad * 8]);
                    acc[dt] = __builtin_amdgcn_mfma_f32_16x16x32_bf16(pf, vf, acc[dt], 0, 0, 0);
                }
            }
        }
        if (haveNext)   // write-late: V regs -> next buffer (vmcnt wait by compiler)
            *(u16x8*)(&Vt_lds[cur ^ 1][vd * KSTR + vkg * 8]) = vreg;
        __syncthreads();   // one barrier/tile: drains next-tile glds, publishes Vt
    }

#pragma unroll
    for (int r = 0; r < 4; ++r) {
        float rs = lsum[r];    // epilogue cross-lane sum reduce (deferred from loop)
#pragma unroll
        for (int off = 1; off <= 8; off <<= 1) rs += __shfl_xor(rs, off, 64);
        const float inv = 1.f / rs;
        const long row = tokbase + qbase + quad * 4 + r;
#pragma unroll
        for (int dt = 0; dt < 4; ++dt)
            Ob[row * 1024 + h * 64 + dt * 16 + l16] = f2bf(acc[dt][r] * inv);
    }
}

// ---------------------------------------------------------------- launch
extern "C" void kernel_launch(void* const* d_in, const int* in_sizes, int n_in,
                              void* d_out, int out_size, void* d_ws, size_t ws_size,
                              hipStream_t stream) {
    u16* ws = (u16*)d_ws;
    // ---- workspace layout (u16 elements) ----
    u16* Wt_attn  = ws + 0;          // 3072x1024
    u16* Wt_self  = ws + 3145728;    // 1024x1024
    u16* Wt_q     = ws + 4194304;    // 1024x1024
    u16* Wt_kv    = ws + 5242880;    // 2048x1024
    u16* Wt_cross = ws + 7340032;    // 1024x1024
    u16* Wt_fc    = ws + 8388608;    // 4096x1024
    u16* Wt_mlp   = ws + 12582912;   // 1024x4096 (ends 16777216)
    u16* qkv      = ws + 16777216;   // 4096x3072 (dead after self-attn)
    u16* q2       = ws + 16777216;   // 4096x1024 (reuse)
    u16* kv2      = ws + 20971520;   // 4096x2048 (reuse)
    u16* x2       = ws + 16777216;   // 4096x1024 (reuse; live into MLP)
    u16* hbuf     = ws + 20971520;   // 4096x4096 (reuse; ends 37748736)
    u16* abuf     = ws + 29360128;   // 4096x1024
    u16* x1       = ws + 33554432;   // 4096x1024 (ends 37748736)
    u16* xb       = ws + 37748736;   // 4096x1024 (converted x; dead after self-proj)
    u16* y3       = ws + 37748736;   // 4096x1024 (MLP out pre-LN; reuses xb slot)
    u16* ctxb     = ws + 41943040;   // 4096x1024 (converted ctx)
    u16* P        = ws + 46137344;   // param slots
    u16* cab = P;            u16* spb = P + 4096;  u16* qb  = P + 8192;
    u16* kvb = P + 12288;    u16* cpb = P + 16384; u16* fcb = P + 20480;
    u16* mpb = P + 24576;
    u16* l1g = P + 28672;  u16* l1b = P + 32768;
    u16* l2g = P + 36864;  u16* l2b = P + 40960;
    u16* l3g = P + 45056;  u16* l3b = P + 49152;
    int* flag = (int*)(ws + 46137344 + 53248);

    const dim3 tb(256);
    const dim3 tg(512);
    const int NTOK = 4096;

    // ---- dtype sniff on x ----
    sniff_kernel<<<1, 64, 0, stream>>>((const u32*)d_in[0], flag);

    // ---- convert activations + params to bf16 (single batched launch) ----
    CvtPack pp;
    pp.src[0] = d_in[0];  pp.dst[0] = xb;   pp.n[0] = NTOK * 1024;
    pp.src[1] = d_in[1];  pp.dst[1] = ctxb; pp.n[1] = NTOK * 1024;
    pp.src[2] = d_in[3];  pp.dst[2] = cab;  pp.n[2] = 3072;
    pp.src[3] = d_in[5];  pp.dst[3] = spb;  pp.n[3] = 1024;
    pp.src[4] = d_in[7];  pp.dst[4] = qb;   pp.n[4] = 1024;
    pp.src[5] = d_in[9];  pp.dst[5] = kvb;  pp.n[5] = 2048;
    pp.src[6] = d_in[11]; pp.dst[6] = cpb;  pp.n[6] = 1024;
    pp.src[7] = d_in[13]; pp.dst[7] = fcb;  pp.n[7] = 4096;
    pp.src[8] = d_in[15]; pp.dst[8] = mpb;  pp.n[8] = 1024;
    pp.src[9] = d_in[16]; pp.dst[9] = l1g;  pp.n[9] = 1024;
    pp.src[10] = d_in[17]; pp.dst[10] = l1b; pp.n[10] = 1024;
    pp.src[11] = d_in[18]; pp.dst[11] = l2g; pp.n[11] = 1024;
    pp.src[12] = d_in[19]; pp.dst[12] = l2b; pp.n[12] = 1024;
    pp.src[13] = d_in[20]; pp.dst[13] = l3g; pp.n[13] = 1024;
    pp.src[14] = d_in[21]; pp.dst[14] = l3b; pp.n[14] = 1024;
    cvt_many<<<dim3(256, 15), tb, 0, stream>>>(pp, flag);

    // ---- weight transposes (+convert): W[K,N] -> Wt[N,K] ----
    transpose_cv<<<dim3(96, 32),  tb, 0, stream>>>(d_in[2],  Wt_attn,  1024, 3072, flag);
    transpose_cv<<<dim3(32, 32),  tb, 0, stream>>>(d_in[4],  Wt_self,  1024, 1024, flag);
    transpose_cv<<<dim3(32, 32),  tb, 0, stream>>>(d_in[6],  Wt_q,     1024, 1024, flag);
    transpose_cv<<<dim3(64, 32),  tb, 0, stream>>>(d_in[8],  Wt_kv,    1024, 2048, flag);
    transpose_cv<<<dim3(32, 32),  tb, 0, stream>>>(d_in[10], Wt_cross, 1024, 1024, flag);
    transpose_cv<<<dim3(128, 32), tb, 0, stream>>>(d_in[12], Wt_fc,    1024, 4096, flag);
    transpose_cv<<<dim3(32, 128), tb, 0, stream>>>(d_in[14], Wt_mlp,   4096, 1024, flag);

    // --- causal self-attention ---
    gemm_big<0><<<dim3(12, 16), tg, 0, stream>>>(xb, Wt_attn, cab, nullptr, qkv, 3072, 1024);
    attn3<true><<<dim3(8, 16, 4), tg, 0, stream>>>(qkv, qkv + 1024, qkv + 2048, abuf,
                                                   3072, 3072, 1024);
    gemm2<128, 128, 1><<<dim3(8, 32), tg, 0, stream>>>(abuf, Wt_self, spb, xb, x1, 1024, 1024);
    ln_kernel<<<NTOK, tb, 0, stream>>>(x1, l1g, l1b);

    // --- cross-attention ---
    gemm2<128, 128, 0><<<dim3(8, 32),  tg, 0, stream>>>(x1,   Wt_q,  qb,  nullptr, q2,  1024, 1024);
    gemm2<128, 256, 0><<<dim3(8, 32), tg, 0, stream>>>(ctxb, Wt_kv, kvb, nullptr, kv2, 2048, 1024);
    attn3<false><<<dim3(8, 16, 4), tg, 0, stream>>>(q2, kv2, kv2 + 1024, abuf,
                                                    1024, 2048, 1024);
    gemm2<128, 128, 1><<<dim3(8, 32), tg, 0, stream>>>(abuf, Wt_cross, cpb, x1, x2, 1024, 1024);
    ln_kernel<<<NTOK, tb, 0, stream>>>(x2, l2g, l2b);

    // --- MLP ---
    gemm_big<2><<<dim3(16, 16), tg, 0, stream>>>(x2, Wt_fc, fcb, nullptr, hbuf, 4096, 1024);
    gemm2<128, 128, 1><<<dim3(8, 32), tg, 0, stream>>>(hbuf, Wt_mlp, mpb, x2, y3, 1024, 4096);
    ln_out_kernel<<<NTOK, tb, 0, stream>>>(y3, l3g, l3b, d_out, flag);
}